// Round 6
// baseline (232.901 us; speedup 1.0000x reference)
//
#include <hip/hip_runtime.h>
#include <hip/hip_cooperative_groups.h>

namespace cg = cooperative_groups;

// DotPred: score[t,e] = sum_d (x[src[t,e],d] - x[dst[t,e],d]) / sqrt(D)
//        = (rowsum(x)[src] - rowsum(x)[dst]) * (1/sqrt(D))
// Single cooperative kernel: phase 1 rowsums -> grid.sync() -> phase 2 edges.
// Indices arrive as int32 (JAX x64 disabled; harness: integer -> const int*).

#define IN_DIM 128
#define INV_SQRT_D 0.08838834764831843f  // 1/sqrt(128)

typedef float fx4 __attribute__((ext_vector_type(4)));
typedef int   ix4 __attribute__((ext_vector_type(4)));

// 1024 blocks x 256 threads: 4 blocks/CU (16 waves/CU) — co-resident for grid.sync.
__global__ __launch_bounds__(256, 4)
void fused_kernel(const fx4* __restrict__ x4,
                  const ix4* __restrict__ src4,
                  const ix4* __restrict__ dst4,
                  const int* __restrict__ src,
                  const int* __restrict__ dst,
                  float* __restrict__ S,
                  fx4* __restrict__ out4,
                  float* __restrict__ out,
                  int n_nodes, int n4, int n_edges) {
    cg::grid_group grid = cg::this_grid();
    const int tid = threadIdx.x;

    // ---- Phase 1: rowsums. 32 lanes per row (float4/lane), 8 rows per block pass.
    {
        const int g   = tid >> 5;      // row-group within block (0..7)
        const int col = tid & 31;
        const int rows_per_pass = gridDim.x * 8;
        for (int row = blockIdx.x * 8 + g; row < n_nodes; row += rows_per_pass) {
            const fx4 v = __builtin_nontemporal_load(&x4[(size_t)row * (IN_DIM / 4) + col]);
            float s = (v.x + v.y) + (v.z + v.w);
            // Butterfly within each 32-lane half (xor of bits 0..4 stays in-half).
            #pragma unroll
            for (int off = 16; off > 0; off >>= 1)
                s += __shfl_xor(s, off, 64);
            if (col == 0) S[row] = s;
        }
    }

    __threadfence();   // device-scope: S visible across XCDs
    grid.sync();

    // ---- Phase 2: edge scores, 4 per thread, grid-stride.
    {
        const int stride = gridDim.x * blockDim.x;
        for (int i = blockIdx.x * blockDim.x + tid; i < n4; i += stride) {
            const ix4 sI = __builtin_nontemporal_load(&src4[i]);
            const ix4 dI = __builtin_nontemporal_load(&dst4[i]);
            fx4 o;
            o.x = (S[sI.x] - S[dI.x]) * INV_SQRT_D;
            o.y = (S[sI.y] - S[dI.y]) * INV_SQRT_D;
            o.z = (S[sI.z] - S[dI.z]) * INV_SQRT_D;
            o.w = (S[sI.w] - S[dI.w]) * INV_SQRT_D;
            __builtin_nontemporal_store(o, &out4[i]);
        }
        // Tail (n % 4 != 0) — empty for n=1.5M, kept for robustness.
        if (blockIdx.x == 0 && tid == 0) {
            for (int j = n4 * 4; j < n_edges; ++j)
                out[j] = (S[src[j]] - S[dst[j]]) * INV_SQRT_D;
        }
    }
}

extern "C" void kernel_launch(void* const* d_in, const int* in_sizes, int n_in,
                              void* d_out, int out_size, void* d_ws, size_t ws_size,
                              hipStream_t stream) {
    const fx4* x4   = (const fx4*)d_in[0];
    const int* src  = (const int*)d_in[1];
    const int* dst  = (const int*)d_in[2];
    const ix4* src4 = (const ix4*)d_in[1];
    const ix4* dst4 = (const ix4*)d_in[2];
    fx4*   out4 = (fx4*)d_out;
    float* out  = (float*)d_out;
    float* S    = (float*)d_ws;   // n_nodes floats of scratch (400 KB)

    int n_nodes = in_sizes[0] / IN_DIM;   // 100000
    int n_edges = in_sizes[1];            // T*E = 1.5M
    int n4      = n_edges >> 2;

    void* args[] = {
        (void*)&x4, (void*)&src4, (void*)&dst4, (void*)&src, (void*)&dst,
        (void*)&S, (void*)&out4, (void*)&out,
        (void*)&n_nodes, (void*)&n4, (void*)&n_edges,
    };
    hipLaunchCooperativeKernel((const void*)fused_kernel,
                               dim3(1024), dim3(256), args, 0, stream);
}

// Round 7
// 105.460 us; speedup vs baseline: 2.2084x; 2.2084x over previous
//
#include <hip/hip_runtime.h>

// DotPred: score[t,e] = sum_d (x[src[t,e],d] - x[dst[t,e],d]) / sqrt(D)
//        = (rowsum(x)[src] - rowsum(x)[dst]) * (1/sqrt(D))
// Two-phase: (1) per-node rowsum into d_ws, (2) per-edge gather/subtract.
// Indices arrive as int32 (JAX x64 disabled; harness: integer -> const int*).
//
// R6 post-mortem: cooperative grid.sync() fusion cost ~130us of barrier spin
// (8 non-coherent XCDs) vs ~4us of dispatch gap — reverted to two launches.
// Nontemporal hints (R5) measured neutral — S is not L2-thrashed. Plain loads.

#define IN_DIM 128
#define INV_SQRT_D 0.08838834764831843f  // 1/sqrt(128)

// 32 lanes per row (float4 each = 128 floats), 2 rows per wave, 8 rows per 256-block.
__global__ void rowsum_kernel(const float4* __restrict__ x4,
                              float* __restrict__ S, int n_nodes) {
    const int wave = (blockIdx.x * blockDim.x + threadIdx.x) >> 6;
    const int lane = threadIdx.x & 63;
    const int row  = wave * 2 + (lane >> 5);
    if (row >= n_nodes) return;
    const int col = lane & 31;

    const float4 v = x4[(size_t)row * (IN_DIM / 4) + col];
    float s = (v.x + v.y) + (v.z + v.w);

    // Butterfly within each 32-lane half (xor of bits 0..4 stays in-half).
    #pragma unroll
    for (int off = 16; off > 0; off >>= 1)
        s += __shfl_xor(s, off, 64);

    if (col == 0) S[row] = s;   // lanes 0 and 32 write their rows
}

// 4 edges per thread: int4 index loads, float4 store.
__global__ void edge_kernel4(const int4* __restrict__ src4,
                             const int4* __restrict__ dst4,
                             const float* __restrict__ S,
                             float4* __restrict__ out4, int n4) {
    const int i = blockIdx.x * blockDim.x + threadIdx.x;
    if (i >= n4) return;
    const int4 s = src4[i];
    const int4 d = dst4[i];
    float4 o;
    o.x = (S[s.x] - S[d.x]) * INV_SQRT_D;
    o.y = (S[s.y] - S[d.y]) * INV_SQRT_D;
    o.z = (S[s.z] - S[d.z]) * INV_SQRT_D;
    o.w = (S[s.w] - S[d.w]) * INV_SQRT_D;
    out4[i] = o;
}

// Scalar tail (n % 4 != 0) — never triggers for n=1.5M but kept for robustness.
__global__ void edge_kernel_tail(const int* __restrict__ src,
                                 const int* __restrict__ dst,
                                 const float* __restrict__ S,
                                 float* __restrict__ out, int start, int n) {
    const int i = start + blockIdx.x * blockDim.x + threadIdx.x;
    if (i >= n) return;
    out[i] = (S[src[i]] - S[dst[i]]) * INV_SQRT_D;
}

extern "C" void kernel_launch(void* const* d_in, const int* in_sizes, int n_in,
                              void* d_out, int out_size, void* d_ws, size_t ws_size,
                              hipStream_t stream) {
    const float* x   = (const float*)d_in[0];
    const int*   src = (const int*)d_in[1];
    const int*   dst = (const int*)d_in[2];
    float* out = (float*)d_out;
    float* S   = (float*)d_ws;   // n_nodes floats of scratch (400 KB)

    const int n_nodes = in_sizes[0] / IN_DIM;   // 100000
    const int n_edges = in_sizes[1];            // T*E = 1.5M

    // Phase 1: rowsums. 8 rows per 256-thread block.
    const int grid1 = (n_nodes + 7) / 8;
    rowsum_kernel<<<grid1, 256, 0, stream>>>((const float4*)x, S, n_nodes);

    // Phase 2: edge scores, 4 per thread.
    const int n4 = n_edges >> 2;
    if (n4 > 0) {
        const int grid2 = (n4 + 255) / 256;
        edge_kernel4<<<grid2, 256, 0, stream>>>((const int4*)src, (const int4*)dst,
                                                S, (float4*)out, n4);
    }
    const int tail_start = n4 << 2;
    const int tail = n_edges - tail_start;
    if (tail > 0) {
        edge_kernel_tail<<<1, 256, 0, stream>>>(src, dst, S, out, tail_start, n_edges);
    }
}